// Round 13
// baseline (472.294 us; speedup 1.0000x reference)
//
#include <hip/hip_runtime.h>
#include <stdint.h>

#define C_ 128

typedef __attribute__((ext_vector_type(8))) short short8;
typedef __attribute__((ext_vector_type(4))) float f32x4;
typedef __attribute__((ext_vector_type(4))) unsigned int u32x4;

__device__ __forceinline__ unsigned short f2bf(float x){
  unsigned u = __builtin_bit_cast(unsigned, x);
  return (unsigned short)((u + 0x7FFFu + ((u >> 16) & 1u)) >> 16);
}
__device__ __forceinline__ float bf2f(unsigned short h){
  unsigned u = ((unsigned)h) << 16;
  return __builtin_bit_cast(float, u);
}
__device__ __forceinline__ unsigned cvtpk(float lo, float hi){
  unsigned r;
  asm("v_cvt_pk_bf16_f32 %0, %1, %2" : "=v"(r) : "v"(lo), "v"(hi));
  return r;
}
__device__ __forceinline__ void bar(){
  asm volatile("s_waitcnt lgkmcnt(0)" ::: "memory");
  __builtin_amdgcn_s_barrier();
  asm volatile("" ::: "memory");
}

// mask dtype probe: lengths >= L/2 >= 4, so first 4 mask elems are true.
__device__ __forceinline__ bool mask_is_i32(const void* mask){
  return ((const unsigned*)mask)[0] == 1u;
}

// ---------------- path-score kernel ----------------
__global__ __launch_bounds__(256) void crf_sent(
    const float* __restrict__ logits,
    const float* __restrict__ trans,
    const int*   __restrict__ labels,
    const void*  __restrict__ mask,
    int L,
    const int* __restrict__ startp, const int* __restrict__ endp,
    float* __restrict__ sent)
{
  const int n = blockIdx.x;
  const int tid = threadIdx.x;
  const int start_tag = *startp;
  const int end_tag   = *endp;
  const bool i32m = mask_is_i32(mask);
  const int*  lab  = labels + (size_t)n * L;
  const int*           m32 = (const int*)mask + (size_t)n * L;
  const unsigned char* m8  = (const unsigned char*)mask + (size_t)n * L;
  const float* lrow = logits + (size_t)n * L * C_;

  float s = 0.f;
  for (int t = tid; t < L; t += 256) {
    int mt = i32m ? m32[t] : (int)m8[t];
    if (mt) {
      int lt  = lab[t];
      int mn  = (t + 1 < L) ? (i32m ? m32[t + 1] : (int)m8[t + 1]) : 0;
      int nxt = mn ? lab[t + 1] : end_tag;
      s += lrow[(size_t)t * C_ + lt] + trans[(size_t)nxt * C_ + lt];
    }
  }
  if (tid == 0) s += trans[(size_t)lab[0] * C_ + start_tag];

  for (int m = 1; m < 64; m <<= 1) s += __shfl_xor(s, m, 64);
  __shared__ float red[4];
  if ((tid & 63) == 0) red[tid >> 6] = s;
  __syncthreads();
  if (tid == 0) sent[n] = (red[0] + red[1]) + (red[2] + red[3]);
}

// ---------------- 8-wave j-split scan: 16 samples / 512-thread block, 32 blocks ------
// r12 base (green) + two chain cuts:
//  1. p-pipelining: p for step t is computed at step t-1 (exp2 runs off the critical
//     path, overlapping the MFMA/lgkm wait). vmcnt(1) after issuing load t+2
//     guarantees LV[t+1] is resident.
//  2. 4 independent MFMA accumulators (tree-summed) instead of two 2-deep chains.
// Eager renorm every 8 steps (lazy renorm blacklisted at 8 waves: r10/r11 NaN).
__global__ __launch_bounds__(512, 1) void crf_scan(
    const float* __restrict__ logits,
    const float* __restrict__ trans,
    const void*  __restrict__ mask,
    const float* __restrict__ sent,
    float* __restrict__ out,
    int L,
    const int* __restrict__ startp, const int* __restrict__ endp)
{
  __shared__ unsigned st[2 * 1024];   // 8 KB state, double-buffered, chunk-swizzled
  __shared__ float mred[16][8];

  const int tid = threadIdx.x;
  const int w   = tid >> 6;     // wave 0..7: owns tags [16w,16w+16)
  const int l   = tid & 63;
  const int lj  = l & 15;       // sample within block
  const int lg  = l >> 4;       // 0..3
  const int j0  = 16 * w + 4 * lg;
  const int n0  = blockIdx.x * 16;
  const int start_tag = *startp;
  const int end_tag   = *endp;
  const bool i32m = mask_is_i32(mask);
  const float LN2 = 0.69314718055994530942f;

  // ---- length of sample lj (each wave redundantly) ----
  int cnt = 0;
  {
    const int seg = L >> 2;
    if (i32m) {
      const int4* m4 = (const int4*)((const int*)mask + (size_t)(n0 + lj) * L + lg * seg);
      for (int i = 0; i < (seg >> 2); i++) {
        int4 v = m4[i];
        cnt += (v.x != 0) + (v.y != 0) + (v.z != 0) + (v.w != 0);
      }
    } else {
      const unsigned* mr = (const unsigned*)((const unsigned char*)mask + (size_t)(n0 + lj) * L + lg * seg);
      for (int i = 0; i < (seg >> 2); i++) cnt += __popc(mr[i]);
    }
    cnt += __shfl_xor(cnt, 16);
    cnt += __shfl_xor(cnt, 32);
  }
  const int len_n = cnt;
  int mn = len_n;
  mn = min(mn, __shfl_xor(mn, 1));
  mn = min(mn, __shfl_xor(mn, 2));
  mn = min(mn, __shfl_xor(mn, 4));
  mn = min(mn, __shfl_xor(mn, 8));
  const int T_main = (mn - 2) & ~1;

  // ---- A-frags: E^T rows [16w,16w+16), natural k-map k=32ks+8lg+e ----
  short8 af[4];
  #pragma unroll
  for (int ks = 0; ks < 4; ks++) {
    const float* tp = trans + (size_t)(16 * w + lj) * C_ + 32 * ks + 8 * lg;
    f32x4 e0 = *(const f32x4*)tp;
    f32x4 e1 = *(const f32x4*)(tp + 4);
    short8 f;
    #pragma unroll
    for (int i = 0; i < 4; i++) f[i] = (short)f2bf(expf(e0[i]));
    #pragma unroll
    for (int i = 0; i < 4; i++) f[4 + i] = (short)f2bf(expf(e1[i]));
    af[ks] = f;
  }

  // ---- init state: zeros + 1.0 at start_tag, in st[0] ----
  ((u32x4*)st)[tid] = (u32x4){0, 0, 0, 0};
  bar();
  if (tid < 16) {
    int phys = ((start_tag >> 3) ^ tid) & 15;
    st[tid * 64 + phys * 4 + ((start_tag & 7) >> 1)] =
        (start_tag & 1) ? 0x3F800000u : 0x00003F80u;
  }
  bar();

  unsigned prev0 = 0, prev1 = 0;
  #pragma unroll
  for (int i = 0; i < 4; i++)
    if (j0 + i == start_tag) {
      if (i == 0) prev0 |= 0x3F80u;
      if (i == 1) prev0 |= 0x3F80u << 16;
      if (i == 2) prev1 |= 0x3F80u;
      if (i == 3) prev1 |= 0x3F80u << 16;
    }

  // ---- LDS offsets (u32 units), 16B-chunk XOR swizzle: phys = logical ^ lj ----
  const int wr_off = lj * 64 + ((((2 * w + (lg >> 1)) ^ lj) & 15) << 2) + ((lg & 1) << 1);
  const int rd0 = lj * 64 + ((((0 + lg) ^ lj) & 15) << 2);
  const int rd1 = lj * 64 + ((((4 + lg) ^ lj) & 15) << 2);
  const int rd2 = lj * 64 + ((((8 + lg) ^ lj) & 15) << 2);
  const int rd3 = lj * 64 + ((((12 + lg) ^ lj) & 15) << 2);

  const float L2E = 1.44269504088896340736f;
  const float NC  = -8.0f * L2E;

  // ---- logits: lane loads its own 4 tags: [n0+lj][t][j0..j0+3] ----
  const float* lbase = logits + (size_t)(n0 + lj) * L * C_ + j0;
  f32x4 lvA, lvB;
  asm volatile("global_load_dwordx4 %0, %1, off" : "=v"(lvA) : "v"(lbase));
  asm volatile("global_load_dwordx4 %0, %1, off" : "=v"(lvB) : "v"(lbase + C_));

  // prologue: p_cur = exp2(L2E*LV0 - 8*L2E)  (wait leaves LV1's load in flight)
  float pc0, pc1, pc2, pc3;
  asm volatile("s_waitcnt vmcnt(1)" ::: "memory");
  __builtin_amdgcn_sched_barrier(0);
  pc0 = __builtin_amdgcn_exp2f(fmaf(lvA[0], L2E, NC));
  pc1 = __builtin_amdgcn_exp2f(fmaf(lvA[1], L2E, NC));
  pc2 = __builtin_amdgcn_exp2f(fmaf(lvA[2], L2E, NC));
  pc3 = __builtin_amdgcn_exp2f(fmaf(lvA[3], L2E, NC));

  float lm = 0.f;

#define SCAN_STEP(T, LVN, CUR, TAILF)                                             \
  {                                                                               \
    /* state reads issued first */                                                \
    const unsigned* sc = st + (CUR) * 1024;                                       \
    u32x4 b0 = *(const u32x4*)&sc[rd0];                                           \
    u32x4 b1 = *(const u32x4*)&sc[rd1];                                           \
    u32x4 b2 = *(const u32x4*)&sc[rd2];                                           \
    u32x4 b3 = *(const u32x4*)&sc[rd3];                                           \
    { /* issue load for step T+2 into the slot LVN will vacate next iter */       \
      int ts = TAILF ? min((T) + 2, L - 1) : ((T) + 2);                           \
      const float* lp = lbase + (size_t)ts * C_;                                  \
      asm volatile("global_load_dwordx4 %0, %1, off" : "=v"(LVN##_next) : "v"(lp)); \
    }                                                                             \
    asm volatile("s_waitcnt vmcnt(1)" ::: "memory");                              \
    __builtin_amdgcn_sched_barrier(0);                                            \
    /* p for step T+1 (off the critical path: overlaps MFMA/lgkm wait) */         \
    float pn0 = __builtin_amdgcn_exp2f(fmaf(LVN[0], L2E, NC));                    \
    float pn1 = __builtin_amdgcn_exp2f(fmaf(LVN[1], L2E, NC));                    \
    float pn2 = __builtin_amdgcn_exp2f(fmaf(LVN[2], L2E, NC));                    \
    float pn3 = __builtin_amdgcn_exp2f(fmaf(LVN[3], L2E, NC));                    \
    f32x4 z = {0.f, 0.f, 0.f, 0.f};                                               \
    f32x4 a0 = __builtin_amdgcn_mfma_f32_16x16x32_bf16(af[0], __builtin_bit_cast(short8, b0), z, 0, 0, 0); \
    f32x4 a1 = __builtin_amdgcn_mfma_f32_16x16x32_bf16(af[1], __builtin_bit_cast(short8, b1), z, 0, 0, 0); \
    f32x4 a2 = __builtin_amdgcn_mfma_f32_16x16x32_bf16(af[2], __builtin_bit_cast(short8, b2), z, 0, 0, 0); \
    f32x4 a3 = __builtin_amdgcn_mfma_f32_16x16x32_bf16(af[3], __builtin_bit_cast(short8, b3), z, 0, 0, 0); \
    float wv0 = ((a0[0] + a1[0]) + (a2[0] + a3[0])) * pc0;                        \
    float wv1 = ((a0[1] + a1[1]) + (a2[1] + a3[1])) * pc1;                        \
    float wv2 = ((a0[2] + a1[2]) + (a2[2] + a3[2])) * pc2;                        \
    float wv3 = ((a0[3] + a1[3]) + (a2[3] + a3[3])) * pc3;                        \
    if (((T) & 7) == 7) {                                                         \
      float tm = fmaxf(fmaxf(wv0, wv1), fmaxf(wv2, wv3));                         \
      tm = fmaxf(tm, __shfl_xor(tm, 16));                                         \
      tm = fmaxf(tm, __shfl_xor(tm, 32));                                         \
      if (lg == 0) mred[lj][w] = tm;                                              \
      bar();                                                                      \
      f32x4 ma = *(const f32x4*)&mred[lj][0];                                     \
      f32x4 mb = *(const f32x4*)&mred[lj][4];                                     \
      float m = fmaxf(fmaxf(fmaxf(ma[0], ma[1]), fmaxf(ma[2], ma[3])),            \
                      fmaxf(fmaxf(mb[0], mb[1]), fmaxf(mb[2], mb[3])));           \
      float rm = __builtin_amdgcn_rcpf(m);                                        \
      wv0 *= rm; wv1 *= rm; wv2 *= rm; wv3 *= rm;                                 \
      if (!(TAILF) || (T) < len_n) lm += LN2 * __builtin_amdgcn_logf(m);          \
    }                                                                             \
    unsigned pk0 = cvtpk(wv0, wv1);                                               \
    unsigned pk1 = cvtpk(wv2, wv3);                                               \
    if (TAILF) {                                                                  \
      bool alive = (T) < len_n;                                                   \
      pk0 = alive ? pk0 : prev0;                                                  \
      pk1 = alive ? pk1 : prev1;                                                  \
    }                                                                             \
    *(unsigned long long*)&st[((CUR) ^ 1) * 1024 + wr_off] =                      \
        ((unsigned long long)pk1 << 32) | pk0;                                    \
    prev0 = pk0; prev1 = pk1;                                                     \
    pc0 = pn0; pc1 = pn1; pc2 = pn2; pc3 = pn3;                                   \
    bar();                                                                        \
  }

  // LVN = buffer holding LV[T+1]; LVN_next = buffer to receive LV[T+2]
#define lvB_next lvA
#define lvA_next lvB
  for (int t = 0; t < T_main; t += 2) {
    SCAN_STEP(t,     lvB, 0, false);
    SCAN_STEP(t + 1, lvA, 1, false);
  }
  for (int t = T_main; t < L; t += 2) {
    SCAN_STEP(t,     lvB, 0, true);
    SCAN_STEP(t + 1, lvA, 1, true);
  }
#undef lvA_next
#undef lvB_next
#undef SCAN_STEP

  // ---- epilogue: per-lane 4-tag partial of sum_j A_j * exp(T[end,j]) ----
  {
    const float* te = trans + (size_t)end_tag * C_ + j0;
    float es = bf2f((unsigned short)(prev0 & 0xffff)) * expf(te[0])
             + bf2f((unsigned short)(prev0 >> 16))    * expf(te[1])
             + bf2f((unsigned short)(prev1 & 0xffff)) * expf(te[2])
             + bf2f((unsigned short)(prev1 >> 16))    * expf(te[3]);
    es += __shfl_xor(es, 16);
    es += __shfl_xor(es, 32);
    if (lg == 0) mred[lj][w] = es;
    bar();
    if (w == 0 && lg == 0) {
      f32x4 a = *(const f32x4*)&mred[lj][0];
      f32x4 b = *(const f32x4*)&mred[lj][4];
      float S = ((a[0] + a[1]) + (a[2] + a[3])) + ((b[0] + b[1]) + (b[2] + b[3]));
      float total = 8.0f * (float)len_n + lm + LN2 * __builtin_amdgcn_logf(S);
      out[n0 + lj] = total - sent[n0 + lj];
    }
  }
}

extern "C" void kernel_launch(void* const* d_in, const int* in_sizes, int n_in,
                              void* d_out, int out_size, void* d_ws, size_t ws_size,
                              hipStream_t stream) {
  const float* logits = (const float*)d_in[0];
  const float* trans  = (const float*)d_in[1];
  const int*   labels = (const int*)d_in[2];
  const void*  mask   = (const void*)d_in[3];
  const int* startp = (const int*)d_in[4];
  const int* endp   = (const int*)d_in[5];
  float* out  = (float*)d_out;
  float* sent = (float*)d_ws;

  const int N = out_size;            // 512
  const int L = in_sizes[2] / N;     // 1024

  crf_sent<<<N, 256, 0, stream>>>(logits, trans, labels, mask, L, startp, endp, sent);
  crf_scan<<<N / 16, 512, 0, stream>>>(logits, trans, mask, sent, out, L, startp, endp);
}

// Round 14
// 360.413 us; speedup vs baseline: 1.3104x; 1.3104x over previous
//
#include <hip/hip_runtime.h>
#include <stdint.h>

#define C_  128
#define SMP 8    // samples per block (lanes lj and lj+8 duplicate sample lj&7)

typedef __attribute__((ext_vector_type(8))) short short8;
typedef __attribute__((ext_vector_type(4))) float f32x4;
typedef __attribute__((ext_vector_type(4))) unsigned int u32x4;

__device__ __forceinline__ unsigned short f2bf(float x){
  unsigned u = __builtin_bit_cast(unsigned, x);
  return (unsigned short)((u + 0x7FFFu + ((u >> 16) & 1u)) >> 16);
}
__device__ __forceinline__ float bf2f(unsigned short h){
  unsigned u = ((unsigned)h) << 16;
  return __builtin_bit_cast(float, u);
}
__device__ __forceinline__ unsigned cvtpk(float lo, float hi){
  unsigned r;
  asm("v_cvt_pk_bf16_f32 %0, %1, %2" : "=v"(r) : "v"(lo), "v"(hi));
  return r;
}
__device__ __forceinline__ void bar(){
  asm volatile("s_waitcnt lgkmcnt(0)" ::: "memory");
  __builtin_amdgcn_s_barrier();
  asm volatile("" ::: "memory");
}

// mask dtype probe: lengths >= L/2 >= 4, so first 4 mask elems are true.
__device__ __forceinline__ bool mask_is_i32(const void* mask){
  return ((const unsigned*)mask)[0] == 1u;
}

// ---------------- path-score kernel ----------------
__global__ __launch_bounds__(256) void crf_sent(
    const float* __restrict__ logits,
    const float* __restrict__ trans,
    const int*   __restrict__ labels,
    const void*  __restrict__ mask,
    int L,
    const int* __restrict__ startp, const int* __restrict__ endp,
    float* __restrict__ sent)
{
  const int n = blockIdx.x;
  const int tid = threadIdx.x;
  const int start_tag = *startp;
  const int end_tag   = *endp;
  const bool i32m = mask_is_i32(mask);
  const int*  lab  = labels + (size_t)n * L;
  const int*           m32 = (const int*)mask + (size_t)n * L;
  const unsigned char* m8  = (const unsigned char*)mask + (size_t)n * L;
  const float* lrow = logits + (size_t)n * L * C_;

  float s = 0.f;
  for (int t = tid; t < L; t += 256) {
    int mt = i32m ? m32[t] : (int)m8[t];
    if (mt) {
      int lt  = lab[t];
      int mn  = (t + 1 < L) ? (i32m ? m32[t + 1] : (int)m8[t + 1]) : 0;
      int nxt = mn ? lab[t + 1] : end_tag;
      s += lrow[(size_t)t * C_ + lt] + trans[(size_t)nxt * C_ + lt];
    }
  }
  if (tid == 0) s += trans[(size_t)lab[0] * C_ + start_tag];

  for (int m = 1; m < 64; m <<= 1) s += __shfl_xor(s, m, 64);
  __shared__ float red[4];
  if ((tid & 63) == 0) red[tid >> 6] = s;
  __syncthreads();
  if (tid == 0) sent[n] = (red[0] + red[1]) + (red[2] + red[3]);
}

// ---------------- 8-wave j-split scan: 8 samples / 512-thread block, 64 blocks -------
// r12 (green) + ONE change: SMP=8 with lane duplication (sample = lj&7). Paired lanes
// (lj, lj+8) read IDENTICAL LDS addresses -> same-address broadcast halves the LDS
// read-pipe time per ds_read_b128 (1KB -> 512B distinct). Bank coverage stays exact:
// for fixed lg, the 8 rows' swizzled chunks lg^s cover all 8 bank-quads. State writes
// and final out writes predicated on lj<8. Eager renorm (lazy blacklisted: r10/r11).
__global__ __launch_bounds__(512, 1) void crf_scan(
    const float* __restrict__ logits,
    const float* __restrict__ trans,
    const void*  __restrict__ mask,
    const float* __restrict__ sent,
    float* __restrict__ out,
    int L,
    const int* __restrict__ startp, const int* __restrict__ endp)
{
  __shared__ unsigned st[2 * SMP * 64];   // 4 KB state, double-buffered, chunk-swizzled
  __shared__ float mred[SMP][8];

  const int tid = threadIdx.x;
  const int w   = tid >> 6;     // wave 0..7: owns tags [16w,16w+16)
  const int l   = tid & 63;
  const int lj  = l & 15;
  const int s_  = lj & 7;       // sample within block (duplicated across lj/lj+8)
  const int lg  = l >> 4;       // 0..3
  const int j0  = 16 * w + 4 * lg;
  const int n0  = blockIdx.x * SMP;
  const int start_tag = *startp;
  const int end_tag   = *endp;
  const bool i32m = mask_is_i32(mask);
  const float LN2 = 0.69314718055994530942f;

  // ---- length of sample s_ ----
  int cnt = 0;
  {
    const int seg = L >> 2;
    if (i32m) {
      const int4* m4 = (const int4*)((const int*)mask + (size_t)(n0 + s_) * L + lg * seg);
      for (int i = 0; i < (seg >> 2); i++) {
        int4 v = m4[i];
        cnt += (v.x != 0) + (v.y != 0) + (v.z != 0) + (v.w != 0);
      }
    } else {
      const unsigned* mr = (const unsigned*)((const unsigned char*)mask + (size_t)(n0 + s_) * L + lg * seg);
      for (int i = 0; i < (seg >> 2); i++) cnt += __popc(mr[i]);
    }
    cnt += __shfl_xor(cnt, 16);
    cnt += __shfl_xor(cnt, 32);
  }
  const int len_n = cnt;
  int mn = len_n;
  mn = min(mn, __shfl_xor(mn, 1));
  mn = min(mn, __shfl_xor(mn, 2));
  mn = min(mn, __shfl_xor(mn, 4));
  mn = min(mn, __shfl_xor(mn, 8));
  const int T_main = (mn - 2) & ~1;

  // ---- A-frags: E^T rows [16w,16w+16), natural k-map k=32ks+8lg+e ----
  short8 af[4];
  #pragma unroll
  for (int ks = 0; ks < 4; ks++) {
    const float* tp = trans + (size_t)(16 * w + lj) * C_ + 32 * ks + 8 * lg;
    f32x4 e0 = *(const f32x4*)tp;
    f32x4 e1 = *(const f32x4*)(tp + 4);
    short8 f;
    #pragma unroll
    for (int i = 0; i < 4; i++) f[i] = (short)f2bf(expf(e0[i]));
    #pragma unroll
    for (int i = 0; i < 4; i++) f[4 + i] = (short)f2bf(expf(e1[i]));
    af[ks] = f;
  }

  // ---- init state: zeros + 1.0 at start_tag, in st[0] ----
  if (tid < 256) ((u32x4*)st)[tid] = (u32x4){0, 0, 0, 0};
  bar();
  if (tid < SMP) {
    int phys = ((start_tag >> 3) ^ tid) & 15;
    st[tid * 64 + phys * 4 + ((start_tag & 7) >> 1)] =
        (start_tag & 1) ? 0x3F800000u : 0x00003F80u;
  }
  bar();

  unsigned prev0 = 0, prev1 = 0;
  #pragma unroll
  for (int i = 0; i < 4; i++)
    if (j0 + i == start_tag) {
      if (i == 0) prev0 |= 0x3F80u;
      if (i == 1) prev0 |= 0x3F80u << 16;
      if (i == 2) prev1 |= 0x3F80u;
      if (i == 3) prev1 |= 0x3F80u << 16;
    }

  // ---- LDS offsets (u32 units), 16B-chunk XOR swizzle: phys = logical ^ s_ ----
  const int wr_off = s_ * 64 + ((((2 * w + (lg >> 1)) ^ s_) & 15) << 2) + ((lg & 1) << 1);
  const int rd0 = s_ * 64 + ((((0 + lg) ^ s_) & 15) << 2);
  const int rd1 = s_ * 64 + ((((4 + lg) ^ s_) & 15) << 2);
  const int rd2 = s_ * 64 + ((((8 + lg) ^ s_) & 15) << 2);
  const int rd3 = s_ * 64 + ((((12 + lg) ^ s_) & 15) << 2);
  const bool wlane = (lj < 8);

  // ---- logits: lane loads its sample's 4 tags (dup lanes coalesce to same line) ----
  const float* lbase = logits + (size_t)(n0 + s_) * L * C_ + j0;
  f32x4 lvA, lvB;
  asm volatile("global_load_dwordx4 %0, %1, off" : "=v"(lvA) : "v"(lbase));
  asm volatile("global_load_dwordx4 %0, %1, off" : "=v"(lvB) : "v"(lbase + C_));

  const float L2E = 1.44269504088896340736f;
  const float NC  = -8.0f * L2E;
  float lm = 0.f;

#define SCAN_STEP(T, LV, CUR, TAILF)                                              \
  {                                                                               \
    const unsigned* sc = st + (CUR) * SMP * 64;                                   \
    u32x4 b0 = *(const u32x4*)&sc[rd0];                                           \
    u32x4 b1 = *(const u32x4*)&sc[rd1];                                           \
    u32x4 b2 = *(const u32x4*)&sc[rd2];                                           \
    u32x4 b3 = *(const u32x4*)&sc[rd3];                                           \
    asm volatile("s_waitcnt vmcnt(1)" ::: "memory");                              \
    __builtin_amdgcn_sched_barrier(0);                                            \
    float p0 = __builtin_amdgcn_exp2f(fmaf(LV[0], L2E, NC));                      \
    float p1 = __builtin_amdgcn_exp2f(fmaf(LV[1], L2E, NC));                      \
    float p2 = __builtin_amdgcn_exp2f(fmaf(LV[2], L2E, NC));                      \
    float p3 = __builtin_amdgcn_exp2f(fmaf(LV[3], L2E, NC));                      \
    {                                                                             \
      int ts = TAILF ? min((T) + 2, L - 1) : ((T) + 2);                           \
      const float* lp = lbase + (size_t)ts * C_;                                  \
      asm volatile("global_load_dwordx4 %0, %1, off" : "=v"(LV) : "v"(lp));       \
    }                                                                             \
    f32x4 z = {0.f, 0.f, 0.f, 0.f};                                               \
    f32x4 acc = __builtin_amdgcn_mfma_f32_16x16x32_bf16(af[0], __builtin_bit_cast(short8, b0), z, 0, 0, 0); \
    acc = __builtin_amdgcn_mfma_f32_16x16x32_bf16(af[1], __builtin_bit_cast(short8, b1), acc, 0, 0, 0);     \
    f32x4 ac2 = __builtin_amdgcn_mfma_f32_16x16x32_bf16(af[2], __builtin_bit_cast(short8, b2), z, 0, 0, 0); \
    ac2 = __builtin_amdgcn_mfma_f32_16x16x32_bf16(af[3], __builtin_bit_cast(short8, b3), ac2, 0, 0, 0);     \
    float wv0 = (acc[0] + ac2[0]) * p0;                                           \
    float wv1 = (acc[1] + ac2[1]) * p1;                                           \
    float wv2 = (acc[2] + ac2[2]) * p2;                                           \
    float wv3 = (acc[3] + ac2[3]) * p3;                                           \
    if (((T) & 7) == 7) {                                                         \
      float tm = fmaxf(fmaxf(wv0, wv1), fmaxf(wv2, wv3));                         \
      tm = fmaxf(tm, __shfl_xor(tm, 16));                                         \
      tm = fmaxf(tm, __shfl_xor(tm, 32));                                         \
      if (lg == 0 && wlane) mred[s_][w] = tm;                                     \
      bar();                                                                      \
      f32x4 ma = *(const f32x4*)&mred[s_][0];                                     \
      f32x4 mb = *(const f32x4*)&mred[s_][4];                                     \
      float m = fmaxf(fmaxf(fmaxf(ma[0], ma[1]), fmaxf(ma[2], ma[3])),            \
                      fmaxf(fmaxf(mb[0], mb[1]), fmaxf(mb[2], mb[3])));           \
      float rm = __builtin_amdgcn_rcpf(m);                                        \
      wv0 *= rm; wv1 *= rm; wv2 *= rm; wv3 *= rm;                                 \
      if (!(TAILF) || (T) < len_n) lm += LN2 * __builtin_amdgcn_logf(m);          \
    }                                                                             \
    unsigned pk0 = cvtpk(wv0, wv1);                                               \
    unsigned pk1 = cvtpk(wv2, wv3);                                               \
    if (TAILF) {                                                                  \
      bool alive = (T) < len_n;                                                   \
      pk0 = alive ? pk0 : prev0;                                                  \
      pk1 = alive ? pk1 : prev1;                                                  \
    }                                                                             \
    if (wlane)                                                                    \
      *(unsigned long long*)&st[((CUR) ^ 1) * SMP * 64 + wr_off] =                \
          ((unsigned long long)pk1 << 32) | pk0;                                  \
    prev0 = pk0; prev1 = pk1;                                                     \
    bar();                                                                        \
  }

  for (int t = 0; t < T_main; t += 2) {
    SCAN_STEP(t,     lvA, 0, false);
    SCAN_STEP(t + 1, lvB, 1, false);
  }
  for (int t = T_main; t < L; t += 2) {
    SCAN_STEP(t,     lvA, 0, true);
    SCAN_STEP(t + 1, lvB, 1, true);
  }
#undef SCAN_STEP

  // ---- epilogue: per-lane 4-tag partial of sum_j A_j * exp(T[end,j]) ----
  {
    const float* te = trans + (size_t)end_tag * C_ + j0;
    float es = bf2f((unsigned short)(prev0 & 0xffff)) * expf(te[0])
             + bf2f((unsigned short)(prev0 >> 16))    * expf(te[1])
             + bf2f((unsigned short)(prev1 & 0xffff)) * expf(te[2])
             + bf2f((unsigned short)(prev1 >> 16))    * expf(te[3]);
    es += __shfl_xor(es, 16);
    es += __shfl_xor(es, 32);
    if (lg == 0 && wlane) mred[s_][w] = es;
    bar();
    if (w == 0 && lg == 0 && wlane) {
      f32x4 a = *(const f32x4*)&mred[s_][0];
      f32x4 b = *(const f32x4*)&mred[s_][4];
      float S = ((a[0] + a[1]) + (a[2] + a[3])) + ((b[0] + b[1]) + (b[2] + b[3]));
      float total = 8.0f * (float)len_n + lm + LN2 * __builtin_amdgcn_logf(S);
      out[n0 + s_] = total - sent[n0 + s_];
    }
  }
}

extern "C" void kernel_launch(void* const* d_in, const int* in_sizes, int n_in,
                              void* d_out, int out_size, void* d_ws, size_t ws_size,
                              hipStream_t stream) {
  const float* logits = (const float*)d_in[0];
  const float* trans  = (const float*)d_in[1];
  const int*   labels = (const int*)d_in[2];
  const void*  mask   = (const void*)d_in[3];
  const int* startp = (const int*)d_in[4];
  const int* endp   = (const int*)d_in[5];
  float* out  = (float*)d_out;
  float* sent = (float*)d_ws;

  const int N = out_size;            // 512
  const int L = in_sizes[2] / N;     // 1024

  crf_sent<<<N, 256, 0, stream>>>(logits, trans, labels, mask, L, startp, endp, sent);
  crf_scan<<<N / SMP, 512, 0, stream>>>(logits, trans, mask, sent, out, L, startp, endp);
}

// Round 15
// 350.256 us; speedup vs baseline: 1.3484x; 1.0290x over previous
//
#include <hip/hip_runtime.h>
#include <stdint.h>

#define C_ 128

typedef __attribute__((ext_vector_type(8))) short short8;
typedef __attribute__((ext_vector_type(4))) float f32x4;
typedef __attribute__((ext_vector_type(4))) unsigned int u32x4;

__device__ __forceinline__ unsigned short f2bf(float x){
  unsigned u = __builtin_bit_cast(unsigned, x);
  return (unsigned short)((u + 0x7FFFu + ((u >> 16) & 1u)) >> 16);
}
__device__ __forceinline__ float bf2f(unsigned short h){
  unsigned u = ((unsigned)h) << 16;
  return __builtin_bit_cast(float, u);
}
__device__ __forceinline__ unsigned cvtpk(float lo, float hi){
  unsigned r;
  asm("v_cvt_pk_bf16_f32 %0, %1, %2" : "=v"(r) : "v"(lo), "v"(hi));
  return r;
}
__device__ __forceinline__ void bar(){
  asm volatile("s_waitcnt lgkmcnt(0)" ::: "memory");
  __builtin_amdgcn_s_barrier();
  asm volatile("" ::: "memory");
}

// mask dtype probe: lengths >= L/2 >= 4, so first 4 mask elems are true.
__device__ __forceinline__ bool mask_is_i32(const void* mask){
  return ((const unsigned*)mask)[0] == 1u;
}

// ---------------- path-score kernel ----------------
__global__ __launch_bounds__(256) void crf_sent(
    const float* __restrict__ logits,
    const float* __restrict__ trans,
    const int*   __restrict__ labels,
    const void*  __restrict__ mask,
    int L,
    const int* __restrict__ startp, const int* __restrict__ endp,
    float* __restrict__ sent)
{
  const int n = blockIdx.x;
  const int tid = threadIdx.x;
  const int start_tag = *startp;
  const int end_tag   = *endp;
  const bool i32m = mask_is_i32(mask);
  const int*  lab  = labels + (size_t)n * L;
  const int*           m32 = (const int*)mask + (size_t)n * L;
  const unsigned char* m8  = (const unsigned char*)mask + (size_t)n * L;
  const float* lrow = logits + (size_t)n * L * C_;

  float s = 0.f;
  for (int t = tid; t < L; t += 256) {
    int mt = i32m ? m32[t] : (int)m8[t];
    if (mt) {
      int lt  = lab[t];
      int mn  = (t + 1 < L) ? (i32m ? m32[t + 1] : (int)m8[t + 1]) : 0;
      int nxt = mn ? lab[t + 1] : end_tag;
      s += lrow[(size_t)t * C_ + lt] + trans[(size_t)nxt * C_ + lt];
    }
  }
  if (tid == 0) s += trans[(size_t)lab[0] * C_ + start_tag];

  for (int m = 1; m < 64; m <<= 1) s += __shfl_xor(s, m, 64);
  __shared__ float red[4];
  if ((tid & 63) == 0) red[tid >> 6] = s;
  __syncthreads();
  if (tid == 0) sent[n] = (red[0] + red[1]) + (red[2] + red[3]);
}

// ---------------- 8-wave j-split scan: 16 samples / 512-thread block, 32 blocks ------
// r12 base (green, 355us) + two ISOLATED chain cuts (the good halves of r13):
//  1. 4 independent MFMA accumulators (tree-summed): removes one MFMA dep-latency.
//  2. p-precompute at distance 3: 4 rotating logits buffers, vmcnt(2) waits on a load
//     issued 2 intervals (~1500cy) ago (free); p for step T+1 is computed from the
//     resident LV[T+1] under the MFMA shadow; step T multiplies by the pre-made pc.
// Eager renorm every 8 steps (lazy blacklisted at 8 waves: r10/r11 NaN).
__global__ __launch_bounds__(512, 1) void crf_scan(
    const float* __restrict__ logits,
    const float* __restrict__ trans,
    const void*  __restrict__ mask,
    const float* __restrict__ sent,
    float* __restrict__ out,
    int L,
    const int* __restrict__ startp, const int* __restrict__ endp)
{
  __shared__ unsigned st[2 * 1024];   // 8 KB state, double-buffered, chunk-swizzled
  __shared__ float mred[16][8];

  const int tid = threadIdx.x;
  const int w   = tid >> 6;     // wave 0..7: owns tags [16w,16w+16)
  const int l   = tid & 63;
  const int lj  = l & 15;       // sample within block
  const int lg  = l >> 4;       // 0..3
  const int j0  = 16 * w + 4 * lg;
  const int n0  = blockIdx.x * 16;
  const int start_tag = *startp;
  const int end_tag   = *endp;
  const bool i32m = mask_is_i32(mask);
  const float LN2 = 0.69314718055994530942f;

  // ---- length of sample lj (each wave redundantly) ----
  int cnt = 0;
  {
    const int seg = L >> 2;
    if (i32m) {
      const int4* m4 = (const int4*)((const int*)mask + (size_t)(n0 + lj) * L + lg * seg);
      for (int i = 0; i < (seg >> 2); i++) {
        int4 v = m4[i];
        cnt += (v.x != 0) + (v.y != 0) + (v.z != 0) + (v.w != 0);
      }
    } else {
      const unsigned* mr = (const unsigned*)((const unsigned char*)mask + (size_t)(n0 + lj) * L + lg * seg);
      for (int i = 0; i < (seg >> 2); i++) cnt += __popc(mr[i]);
    }
    cnt += __shfl_xor(cnt, 16);
    cnt += __shfl_xor(cnt, 32);
  }
  const int len_n = cnt;
  int mn = len_n;
  mn = min(mn, __shfl_xor(mn, 1));
  mn = min(mn, __shfl_xor(mn, 2));
  mn = min(mn, __shfl_xor(mn, 4));
  mn = min(mn, __shfl_xor(mn, 8));
  const int T_main = (mn - 3) & ~3;   // multiple of 4; main loop fully alive + safe loads

  // ---- A-frags: E^T rows [16w,16w+16), natural k-map k=32ks+8lg+e ----
  short8 af[4];
  #pragma unroll
  for (int ks = 0; ks < 4; ks++) {
    const float* tp = trans + (size_t)(16 * w + lj) * C_ + 32 * ks + 8 * lg;
    f32x4 e0 = *(const f32x4*)tp;
    f32x4 e1 = *(const f32x4*)(tp + 4);
    short8 f;
    #pragma unroll
    for (int i = 0; i < 4; i++) f[i] = (short)f2bf(expf(e0[i]));
    #pragma unroll
    for (int i = 0; i < 4; i++) f[4 + i] = (short)f2bf(expf(e1[i]));
    af[ks] = f;
  }

  // ---- init state: zeros + 1.0 at start_tag, in st[0] ----
  ((u32x4*)st)[tid] = (u32x4){0, 0, 0, 0};
  bar();
  if (tid < 16) {
    int phys = ((start_tag >> 3) ^ tid) & 15;
    st[tid * 64 + phys * 4 + ((start_tag & 7) >> 1)] =
        (start_tag & 1) ? 0x3F800000u : 0x00003F80u;
  }
  bar();

  unsigned prev0 = 0, prev1 = 0;
  #pragma unroll
  for (int i = 0; i < 4; i++)
    if (j0 + i == start_tag) {
      if (i == 0) prev0 |= 0x3F80u;
      if (i == 1) prev0 |= 0x3F80u << 16;
      if (i == 2) prev1 |= 0x3F80u;
      if (i == 3) prev1 |= 0x3F80u << 16;
    }

  // ---- LDS offsets (u32 units), 16B-chunk XOR swizzle: phys = logical ^ lj ----
  const int wr_off = lj * 64 + ((((2 * w + (lg >> 1)) ^ lj) & 15) << 2) + ((lg & 1) << 1);
  const int rd0 = lj * 64 + ((((0 + lg) ^ lj) & 15) << 2);
  const int rd1 = lj * 64 + ((((4 + lg) ^ lj) & 15) << 2);
  const int rd2 = lj * 64 + ((((8 + lg) ^ lj) & 15) << 2);
  const int rd3 = lj * 64 + ((((12 + lg) ^ lj) & 15) << 2);

  const float L2E = 1.44269504088896340736f;
  const float NC  = -8.0f * L2E;

  // ---- logits: lane loads its own 4 tags; 4 rotating buffers (distance-3) ----
  const float* lbase = logits + (size_t)(n0 + lj) * L * C_ + j0;
  f32x4 lv0, lv1, lv2, lv3;
  asm volatile("global_load_dwordx4 %0, %1, off" : "=v"(lv0) : "v"(lbase));
  asm volatile("global_load_dwordx4 %0, %1, off" : "=v"(lv1) : "v"(lbase + C_));
  asm volatile("global_load_dwordx4 %0, %1, off" : "=v"(lv2) : "v"(lbase + 2 * C_));

  // prologue: p for step 0 (vmcnt(2): lv0 arrived, lv1/lv2 still in flight)
  float pc0, pc1, pc2, pc3;
  asm volatile("s_waitcnt vmcnt(2)" ::: "memory");
  __builtin_amdgcn_sched_barrier(0);
  pc0 = __builtin_amdgcn_exp2f(fmaf(lv0[0], L2E, NC));
  pc1 = __builtin_amdgcn_exp2f(fmaf(lv0[1], L2E, NC));
  pc2 = __builtin_amdgcn_exp2f(fmaf(lv0[2], L2E, NC));
  pc3 = __builtin_amdgcn_exp2f(fmaf(lv0[3], L2E, NC));

  float lm = 0.f;

#define SCAN_STEP(T, LVNXT, LVISS, CUR, TAILF)                                    \
  {                                                                               \
    const unsigned* sc = st + (CUR) * 1024;                                       \
    u32x4 b0 = *(const u32x4*)&sc[rd0];                                           \
    u32x4 b1 = *(const u32x4*)&sc[rd1];                                           \
    u32x4 b2 = *(const u32x4*)&sc[rd2];                                           \
    u32x4 b3 = *(const u32x4*)&sc[rd3];                                           \
    { /* issue load for step T+3 into the buffer freed at step T-1 */             \
      int ts = TAILF ? min((T) + 3, L - 1) : ((T) + 3);                           \
      const float* lp = lbase + (size_t)ts * C_;                                  \
      asm volatile("global_load_dwordx4 %0, %1, off" : "=v"(LVISS) : "v"(lp));    \
    }                                                                             \
    asm volatile("s_waitcnt vmcnt(2)" ::: "memory");  /* LV[T+1] resident */      \
    __builtin_amdgcn_sched_barrier(0);                                            \
    /* p for step T+1 — runs under the MFMA/lgkm shadow, off the chain */         \
    float pn0 = __builtin_amdgcn_exp2f(fmaf(LVNXT[0], L2E, NC));                  \
    float pn1 = __builtin_amdgcn_exp2f(fmaf(LVNXT[1], L2E, NC));                  \
    float pn2 = __builtin_amdgcn_exp2f(fmaf(LVNXT[2], L2E, NC));                  \
    float pn3 = __builtin_amdgcn_exp2f(fmaf(LVNXT[3], L2E, NC));                  \
    f32x4 z = {0.f, 0.f, 0.f, 0.f};                                               \
    f32x4 a0 = __builtin_amdgcn_mfma_f32_16x16x32_bf16(af[0], __builtin_bit_cast(short8, b0), z, 0, 0, 0); \
    f32x4 a1 = __builtin_amdgcn_mfma_f32_16x16x32_bf16(af[1], __builtin_bit_cast(short8, b1), z, 0, 0, 0); \
    f32x4 a2 = __builtin_amdgcn_mfma_f32_16x16x32_bf16(af[2], __builtin_bit_cast(short8, b2), z, 0, 0, 0); \
    f32x4 a3 = __builtin_amdgcn_mfma_f32_16x16x32_bf16(af[3], __builtin_bit_cast(short8, b3), z, 0, 0, 0); \
    float wv0 = ((a0[0] + a1[0]) + (a2[0] + a3[0])) * pc0;                        \
    float wv1 = ((a0[1] + a1[1]) + (a2[1] + a3[1])) * pc1;                        \
    float wv2 = ((a0[2] + a1[2]) + (a2[2] + a3[2])) * pc2;                        \
    float wv3 = ((a0[3] + a1[3]) + (a2[3] + a3[3])) * pc3;                        \
    if (((T) & 7) == 7) {                                                         \
      float tm = fmaxf(fmaxf(wv0, wv1), fmaxf(wv2, wv3));                         \
      tm = fmaxf(tm, __shfl_xor(tm, 16));                                         \
      tm = fmaxf(tm, __shfl_xor(tm, 32));                                         \
      if (lg == 0) mred[lj][w] = tm;                                              \
      bar();                                                                      \
      f32x4 ma = *(const f32x4*)&mred[lj][0];                                     \
      f32x4 mb = *(const f32x4*)&mred[lj][4];                                     \
      float m = fmaxf(fmaxf(fmaxf(ma[0], ma[1]), fmaxf(ma[2], ma[3])),            \
                      fmaxf(fmaxf(mb[0], mb[1]), fmaxf(mb[2], mb[3])));           \
      float rm = __builtin_amdgcn_rcpf(m);                                        \
      wv0 *= rm; wv1 *= rm; wv2 *= rm; wv3 *= rm;                                 \
      if (!(TAILF) || (T) < len_n) lm += LN2 * __builtin_amdgcn_logf(m);          \
    }                                                                             \
    unsigned pk0 = cvtpk(wv0, wv1);                                               \
    unsigned pk1 = cvtpk(wv2, wv3);                                               \
    if (TAILF) {                                                                  \
      bool alive = (T) < len_n;                                                   \
      pk0 = alive ? pk0 : prev0;                                                  \
      pk1 = alive ? pk1 : prev1;                                                  \
    }                                                                             \
    *(unsigned long long*)&st[((CUR) ^ 1) * 1024 + wr_off] =                      \
        ((unsigned long long)pk1 << 32) | pk0;                                    \
    prev0 = pk0; prev1 = pk1;                                                     \
    pc0 = pn0; pc1 = pn1; pc2 = pn2; pc3 = pn3;                                   \
    bar();                                                                        \
  }

  for (int t = 0; t < T_main; t += 4) {
    SCAN_STEP(t,     lv1, lv3, 0, false);
    SCAN_STEP(t + 1, lv2, lv0, 1, false);
    SCAN_STEP(t + 2, lv3, lv1, 0, false);
    SCAN_STEP(t + 3, lv0, lv2, 1, false);
  }
  for (int t = T_main; t < L; t += 4) {
    SCAN_STEP(t,     lv1, lv3, 0, true);
    SCAN_STEP(t + 1, lv2, lv0, 1, true);
    SCAN_STEP(t + 2, lv3, lv1, 0, true);
    SCAN_STEP(t + 3, lv0, lv2, 1, true);
  }
#undef SCAN_STEP

  // ---- epilogue: per-lane 4-tag partial of sum_j A_j * exp(T[end,j]) ----
  {
    const float* te = trans + (size_t)end_tag * C_ + j0;
    float es = bf2f((unsigned short)(prev0 & 0xffff)) * expf(te[0])
             + bf2f((unsigned short)(prev0 >> 16))    * expf(te[1])
             + bf2f((unsigned short)(prev1 & 0xffff)) * expf(te[2])
             + bf2f((unsigned short)(prev1 >> 16))    * expf(te[3]);
    es += __shfl_xor(es, 16);
    es += __shfl_xor(es, 32);
    if (lg == 0) mred[lj][w] = es;
    bar();
    if (w == 0 && lg == 0) {
      f32x4 a = *(const f32x4*)&mred[lj][0];
      f32x4 b = *(const f32x4*)&mred[lj][4];
      float S = ((a[0] + a[1]) + (a[2] + a[3])) + ((b[0] + b[1]) + (b[2] + b[3]));
      float total = 8.0f * (float)len_n + lm + LN2 * __builtin_amdgcn_logf(S);
      out[n0 + lj] = total - sent[n0 + lj];
    }
  }
}

extern "C" void kernel_launch(void* const* d_in, const int* in_sizes, int n_in,
                              void* d_out, int out_size, void* d_ws, size_t ws_size,
                              hipStream_t stream) {
  const float* logits = (const float*)d_in[0];
  const float* trans  = (const float*)d_in[1];
  const int*   labels = (const int*)d_in[2];
  const void*  mask   = (const void*)d_in[3];
  const int* startp = (const int*)d_in[4];
  const int* endp   = (const int*)d_in[5];
  float* out  = (float*)d_out;
  float* sent = (float*)d_ws;

  const int N = out_size;            // 512
  const int L = in_sizes[2] / N;     // 1024

  crf_sent<<<N, 256, 0, stream>>>(logits, trans, labels, mask, L, startp, endp, sent);
  crf_scan<<<N / 16, 512, 0, stream>>>(logits, trans, mask, sent, out, L, startp, endp);
}